// Round 13
// baseline (635.775 us; speedup 1.0000x reference)
//
#include <hip/hip_runtime.h>
#include <hip/hip_cooperative_groups.h>
#include <math.h>

namespace cg = cooperative_groups;

// Problem constants
#define BQ 64
#define NOBJ 5
#define CIN 3
#define IMG_H 64
#define IMG_W 96
#define OH 32
#define OW 48
#define NPAIR 25
#define PP 4
#define CONV_OUT 32

#define NRG 16                          // 32 output rows / 2
#define NPOS 96                         // 2 output rows x 48 cols
#define XK 32                           // padded K (27 real + bias + zeros)
#define X_U32 (NOBJ * NPOS * XK / 2)    // 7680 u32 = 30.7 KB (f16 im2col)
#define X_UNITS (NOBJ * NPOS * 4)       // 1920 8-elem units

#define NPRED (2 * 1600 * PP)           // 12800
#define ADJ_N (BQ * 1600)               // 102400

typedef __fp16   h2 __attribute__((ext_vector_type(2)));
typedef _Float16 half8 __attribute__((ext_vector_type(8)));
typedef float    float4_ __attribute__((ext_vector_type(4)));
typedef unsigned int uint4_ __attribute__((ext_vector_type(4)));

// ---- one (src,b,rg) conv pass: stage f16 im2col into sX, MFMA+combine,
// wave-reduce, store 25x1 partials into T. Identical to the R9-proven body. ----
__device__ __forceinline__ void conv_pass(
    const float* __restrict__ g,     // image base for this (src,b)
    int R0, int src, int b, int rg, int tid,
    half8 wa, half8 wb, h2 w2h01, h2 w2h23,
    unsigned int* sX32, float* __restrict__ T)
{
    const int wave = tid >> 6;
    const int lane = tid & 63;
    const int quad = lane >> 4;
    const int ocl  = lane & 15;
    const int mt   = wave;
    const int p    = mt >> 1;

    __syncthreads();                // protect sX from previous pass's readers

    // ---- build f16 im2col sX[obj][pos][k] directly from global ----
    {
        const int subk = tid & 3;   // invariant under += 512 stepping
        int koff[8], khv[8], kwv[8];
        float padf[8];
        bool kval[8];
        #pragma unroll
        for (int j = 0; j < 8; ++j) {
            int k = subk * 8 + j;
            if (k < 27) {
                int ci = k / 9;
                int r9 = k - ci * 9;
                int kh = r9 / 3;
                int kw = r9 - kh * 3;
                koff[j] = ci * (IMG_H * IMG_W) + kh * IMG_W + kw;
                khv[j] = kh; kwv[j] = kw; kval[j] = true; padf[j] = 0.f;
            } else {
                koff[j] = 0; khv[j] = 0; kwv[j] = 0; kval[j] = false;
                padf[j] = (k == 27) ? 1.0f : 0.f;
            }
        }
        for (int u = tid; u < X_UNITS; u += 512) {
            int pl  = (u >> 2) % NPOS;
            int obj = u / (NPOS * 4);
            int rl  = (pl >= 48) ? 1 : 0;
            int pc  = pl - rl * 48;
            int gr0 = R0 + 2 * rl;
            int gc0 = 2 * pc;
            const float* gp = g + obj * (CIN * IMG_H * IMG_W) + gr0 * IMG_W + gc0;
            float fv[8];
            #pragma unroll
            for (int j = 0; j < 8; ++j) {
                float v = padf[j];
                if (kval[j] && (gr0 + khv[j] < IMG_H) && (gc0 + kwv[j] < IMG_W))
                    v = gp[koff[j]];
                fv[j] = v;
            }
            uint4_ w4;
            w4.x = __builtin_bit_cast(unsigned int, __builtin_amdgcn_cvt_pkrtz(fv[0], fv[1]));
            w4.y = __builtin_bit_cast(unsigned int, __builtin_amdgcn_cvt_pkrtz(fv[2], fv[3]));
            w4.z = __builtin_bit_cast(unsigned int, __builtin_amdgcn_cvt_pkrtz(fv[4], fv[5]));
            w4.w = __builtin_bit_cast(unsigned int, __builtin_amdgcn_cvt_pkrtz(fv[6], fv[7]));
            *(uint4_*)&sX32[(size_t)u * 4] = w4;
        }
    }

    __syncthreads();

    const float4_ zero4 = {0.f, 0.f, 0.f, 0.f};
    const h2 hz = {(__fp16)0.f, (__fp16)0.f};

    float acc[NPAIR];
    #pragma unroll
    for (int q = 0; q < NPAIR; ++q) acc[q] = 0.f;

    #pragma unroll
    for (int nt = 0; nt < 6; ++nt) {    // 2 rows x 3 col-tiles of 16
        const int rl  = nt / 3;
        const int c0  = (nt - rl * 3) * 16;
        const int pos = rl * 48 + c0 + ocl;

        half8 xf[NOBJ];
        h2 ah01[NOBJ], ah23[NOBJ];
        #pragma unroll
        for (int obj = 0; obj < NOBJ; ++obj) {
            xf[obj] = *(const half8*)&sX32[((size_t)(obj * NPOS + pos)) * 16 + quad * 4];
            float4_ a = __builtin_amdgcn_mfma_f32_16x16x32_f16(wa, xf[obj], zero4, 0, 0, 0);
            ah01[obj] = __builtin_amdgcn_cvt_pkrtz(a[0], a[1]);
            ah23[obj] = __builtin_amdgcn_cvt_pkrtz(a[2], a[3]);
        }

        #pragma unroll
        for (int jo = 0; jo < NOBJ; ++jo) {
            float4_ bq = __builtin_amdgcn_mfma_f32_16x16x32_f16(wb, xf[jo], zero4, 0, 0, 0);
            h2 bh01 = __builtin_amdgcn_cvt_pkrtz(bq[0], bq[1]);
            h2 bh23 = __builtin_amdgcn_cvt_pkrtz(bq[2], bq[3]);
            #pragma unroll
            for (int i = 0; i < NOBJ; ++i) {
                h2 s0 = ah01[i] + bh01;                        // v_pk_add_f16
                h2 s1 = ah23[i] + bh23;
                s0 = __builtin_elementwise_max(s0, hz);        // v_pk_max_f16
                s1 = __builtin_elementwise_max(s1, hz);
                float t0 = __builtin_amdgcn_fdot2(s0, w2h01, acc[i * NOBJ + jo], false);
                acc[i * NOBJ + jo] = __builtin_amdgcn_fdot2(s1, w2h23, t0, false);
            }
        }
    }

    // ---- wave-reduce each pair across 64 lanes; plain store (no atomics) ----
    float myv = 0.f;
    #pragma unroll
    for (int q = 0; q < NPAIR; ++q) {
        float rr = acc[q];
        #pragma unroll
        for (int off = 32; off > 0; off >>= 1)
            rr += __shfl_xor(rr, off, 64);
        if (lane == q) myv = rr;
    }
    if (lane < NPAIR)
        T[((((size_t)src * BQ + b) * NRG + rg) * NPAIR + lane) * 8 + mt] = myv;
}

__device__ __forceinline__ void load_weights(
    const float* __restrict__ conv_w, const float* __restrict__ conv_b,
    const float* __restrict__ w2, int tid,
    half8& wa, half8& wb, h2& w2h01, h2& w2h23)
{
    const int lane = tid & 63;
    const int quad = lane >> 4;
    const int ocl  = lane & 15;
    const int mt   = tid >> 6;
    const int p    = mt >> 1;
    const int row  = mt * 16 + ocl;
    #pragma unroll
    for (int j = 0; j < 8; ++j) {
        int k = quad * 8 + j;
        float va = 0.f, vb = 0.f;
        if (k < 27) {
            va = conv_w[row * 54 + k];
            vb = conv_w[row * 54 + 27 + k];
        } else if (k == 27) {
            va = conv_b[row];
        }
        wa[j] = (_Float16)va;
        wb[j] = (_Float16)vb;
    }
    const float* wp = w2 + p * CONV_OUT + (mt & 1) * 16 + quad * 4;
    w2h01 = __builtin_amdgcn_cvt_pkrtz(wp[0], wp[1]);
    w2h23 = __builtin_amdgcn_cvt_pkrtz(wp[2], wp[3]);
}

// ================= cooperative single-dispatch path =================
__global__ __launch_bounds__(512, 8) void fused_all(
    const float* __restrict__ state,
    const float* __restrict__ state_next,
    const float* __restrict__ conv_w,
    const float* __restrict__ conv_b,
    const float* __restrict__ w2,
    const float* __restrict__ b2,
    const float* __restrict__ temp,
    float* __restrict__ T,
    float* __restrict__ out)
{
    __shared__ __align__(16) unsigned int sX32[X_U32];

    const int tid = threadIdx.x;
    const int bid = blockIdx.x;         // 0..1023
    const int rg  = bid & (NRG - 1);
    const int b   = bid >> 4;
    const int R0  = rg * 4;

    if (tid < 100) {                    // adj: 1024 x 100 = 102400
        int a  = bid * 100 + tid;
        int bb = a / 1600;
        int t  = a - bb * 1600;
        out[NPRED + a] = (t / NPAIR == bb) ? 1.0f : 0.0f;
    }

    half8 wa, wb; h2 w2h01, w2h23;
    load_weights(conv_w, conv_b, w2, tid, wa, wb, w2h01, w2h23);

    const size_t boff = (size_t)b * NOBJ * CIN * IMG_H * IMG_W;
    conv_pass(state + boff,      R0, 0, b, rg, tid, wa, wb, w2h01, w2h23, sX32, T);
    conv_pass(state_next + boff, R0, 1, b, rg, tid, wa, wb, w2h01, w2h23, sX32, T);

    __threadfence();
    cg::this_grid().sync();

    int gt = bid * 512 + tid;
    if (gt < NPRED) {
        int pp   = gt & 3;
        int t    = (gt >> 2) % 1600;
        int srci = gt / 6400;
        int bb   = t / NPAIR;
        int pr   = t - bb * NPAIR;
        const float* base = T + ((((size_t)srci * BQ + bb) * NRG) * NPAIR + pr) * 8 + 2 * pp;
        float sum = 0.f;
        #pragma clang loop unroll(disable)
        for (int rgi = 0; rgi < NRG; ++rgi)
            sum += base[rgi * 200] + base[rgi * 200 + 1];
        float logit = sum * (1.0f / (OH * OW)) + b2[pp];
        float x = logit / temp[0];
        out[gt] = 1.0f / (1.0f + expf(-x));
    }
}

// ================= fallback: proven R9 two-dispatch path =================
__global__ __launch_bounds__(512) void conv_split(
    const float* __restrict__ state,
    const float* __restrict__ state_next,
    const float* __restrict__ conv_w,
    const float* __restrict__ conv_b,
    const float* __restrict__ w2,
    float* __restrict__ T,
    float* __restrict__ out)
{
    __shared__ __align__(16) unsigned int sX32[X_U32];

    const int tid = threadIdx.x;
    const int rg  = blockIdx.x;
    const int b   = blockIdx.y;
    const int src = blockIdx.z;
    const int R0  = rg * 4;

    if (src == 1 && tid < 100) {
        int a  = (rg + NRG * b) * 100 + tid;
        int bb = a / 1600;
        int t  = a - bb * 1600;
        out[NPRED + a] = (t / NPAIR == bb) ? 1.0f : 0.0f;
    }

    half8 wa, wb; h2 w2h01, w2h23;
    load_weights(conv_w, conv_b, w2, tid, wa, wb, w2h01, w2h23);

    const float* g = (src == 0 ? state : state_next)
                   + (size_t)b * NOBJ * CIN * IMG_H * IMG_W;
    conv_pass(g, R0, src, b, rg, tid, wa, wb, w2h01, w2h23, sX32, T);
}

__global__ __launch_bounds__(256) void pred_kernel(
    const float* __restrict__ T,
    const float* __restrict__ b2,
    const float* __restrict__ temp,
    float* __restrict__ out)
{
    int idx = blockIdx.x * blockDim.x + threadIdx.x;
    if (idx >= NPRED) return;
    int p   = idx & 3;
    int t   = (idx >> 2) % 1600;
    int src = idx / 6400;
    int bb  = t / NPAIR;
    int pr  = t - bb * NPAIR;
    const float* base = T + ((((size_t)src * BQ + bb) * NRG) * NPAIR + pr) * 8 + 2 * p;
    float sum = 0.f;
    #pragma unroll
    for (int rgi = 0; rgi < NRG; ++rgi)
        sum += base[rgi * 200] + base[rgi * 200 + 1];
    float logit = sum * (1.0f / (OH * OW)) + b2[p];
    float x = logit / temp[0];
    out[idx] = 1.0f / (1.0f + expf(-x));
}

extern "C" void kernel_launch(void* const* d_in, const int* in_sizes, int n_in,
                              void* d_out, int out_size, void* d_ws, size_t ws_size,
                              hipStream_t stream)
{
    const float* state      = (const float*)d_in[0];
    const float* state_next = (const float*)d_in[1];
    const float* conv_w     = (const float*)d_in[2];
    const float* conv_b     = (const float*)d_in[3];
    const float* w2         = (const float*)d_in[4];
    const float* b2         = (const float*)d_in[5];
    // d_in[6] = n_obj (always 5)
    const float* temp       = (const float*)d_in[7];

    float* out = (float*)d_out;
    float* T   = (float*)d_ws;              // [2][64][16][25][8] floats = 1.64 MB

    void* args[] = {
        (void*)&state, (void*)&state_next, (void*)&conv_w, (void*)&conv_b,
        (void*)&w2, (void*)&b2, (void*)&temp, (void*)&T, (void*)&out
    };
    hipError_t err = hipLaunchCooperativeKernel(
        (const void*)fused_all, dim3(BQ * NRG, 1, 1), dim3(512, 1, 1),
        args, 0, stream);

    if (err != hipSuccess) {
        (void)hipGetLastError();            // clear the sticky error
        dim3 grid1(NRG, BQ, 2);
        conv_split<<<grid1, 512, 0, stream>>>(state, state_next, conv_w, conv_b,
                                              w2, T, out);
        pred_kernel<<<(NPRED + 255) / 256, 256, 0, stream>>>(T, b2, temp, out);
    }
}